// Round 6
// baseline (47.835 us; speedup 1.0000x reference)
//
#include <hip/hip_runtime.h>
#include <hip/hip_bf16.h>
#include <cmath>

namespace {

typedef __attribute__((ext_vector_type(8))) short bf16x8;
typedef __attribute__((ext_vector_type(4))) float f32x4;

constexpr float kNegInf = -1000000000.0f;
constexpr float kSlope  = 0.2f;
constexpr float kLog2e  = 1.44269504088896340736f;

__device__ __forceinline__ unsigned short f2bf(float x) {
  unsigned int u = __float_as_uint(x);
  u = (u + 0x7FFFu + ((u >> 16) & 1u)) >> 16;  // RNE
  return (unsigned short)u;
}
// packed pair: returns (bf16(b)<<16) | bf16(a)  via v_cvt_pk_bf16_f32
__device__ __forceinline__ unsigned int f2bf2(float a, float b) {
  __hip_bfloat162 t = __float22bfloat162_rn(float2{a, b});
  union { __hip_bfloat162 h; unsigned int u; } c;
  c.h = t;
  return c.u;
}
// hardware exp2 (v_exp_f32)
__device__ __forceinline__ float exp2_hw(float x) {
#if __has_builtin(__builtin_amdgcn_exp2f)
  return __builtin_amdgcn_exp2f(x);
#else
  float r;
  asm("v_exp_f32 %0, %1\n\ts_nop 1" : "=v"(r) : "v"(x));
  return r;
#endif
}

// ---------------- ws layout ----------------
// [0)      ushort wf[18432]   [W | wa1 wa2] B-frag order, bf16 (wa pre-scaled by log2e)
// [36864)  uint   adjp[512]   bit-packed adjacency
// [38912)  float  wa1[128]    (log2e-scaled)
// [39424)  float  wa2[128]
// [39936)  float  ba[2]       {log2e*Wb.a1, log2e*Wb.a2}

__global__ void prep1(const float* __restrict__ Ww, const float* __restrict__ Wb,
                      const float* __restrict__ a1v, const float* __restrict__ a2v,
                      float* __restrict__ wa1, float* __restrict__ wa2,
                      float* __restrict__ ba) {
  const int k = threadIdx.x;
  if (k < 128) {
    float s1 = 0.f, s2 = 0.f;
    for (int g = 0; g < 128; ++g) {
      const float w = Ww[k * 128 + g];
      s1 = fmaf(w, a1v[g], s1);
      s2 = fmaf(w, a2v[g], s2);
    }
    wa1[k] = s1 * kLog2e;
    wa2[k] = s2 * kLog2e;
  }
  if (k == 128) {
    float s1 = 0.f, s2 = 0.f;
    for (int g = 0; g < 128; ++g) {
      s1 = fmaf(Wb[g], a1v[g], s1);
      s2 = fmaf(Wb[g], a2v[g], s2);
    }
    ba[0] = s1 * kLog2e;
    ba[1] = s2 * kLog2e;
  }
}

__global__ void prep2(const float* __restrict__ Ww, const int* __restrict__ adj,
                      const float* __restrict__ wa1, const float* __restrict__ wa2,
                      unsigned short* __restrict__ wf, unsigned int* __restrict__ adjp) {
  const int tid = blockIdx.x * 256 + threadIdx.x;
  if (tid < 18432) {
    // frag order: wf[g][kc][lane][j] = B[k = kc*32 + (lane>>4)*8 + j][col = g*16 + (lane&15)]
    const int j = tid & 7, l = (tid >> 3) & 63, kc = (tid >> 9) & 3, g = tid >> 11;
    const int k = kc * 32 + ((l >> 4) << 3) + j;
    const int c = l & 15;
    float x;
    if (g < 8) x = Ww[k * 128 + g * 16 + c];
    else       x = (c == 0) ? wa1[k] : (c == 1) ? wa2[k] : 0.f;
    wf[tid] = f2bf(x);
  }
  if (tid < 512) {
    const int row = tid >> 2, wd = tid & 3;
    const int* ap = adj + row * 128 + wd * 32;
    unsigned int bits = 0u;
#pragma unroll
    for (int b = 0; b < 32; ++b) bits |= (ap[b] != 0 ? (1u << b) : 0u);
    adjp[tid] = bits;
  }
}

struct SMemA {
  unsigned short Whs[8][4][64][8];  // 32768 B: Wh in B-frag order
  float f1s[128];                   // 512   (log2 domain)
  float f2s[128];                   // 512   (log2 domain)
  unsigned int adjs[512];           // 2048
};
union SMemU {
  SMemA a;
  float stage[4][16][132];          // 33792 B — aliases Whs+f1s+f2s (dead by epilogue)
};                                   // sizeof = 35840 -> 4 blocks/CU

__global__ __launch_bounds__(256, 4) void gat_mfma(
    const float* __restrict__ h,     // [BS][128][128]
    const float* __restrict__ Wb,    // [128]
    const float* __restrict__ abp,   // [1]
    const unsigned short* __restrict__ wf,
    const unsigned int* __restrict__ adjp,
    const float* __restrict__ ba,
    float* __restrict__ out) {       // [BS][128][128]
  __shared__ SMemU smu;
  SMemA& sm = smu.a;
  const int t    = threadIdx.x;
  const int lane = t & 63;
  const int w    = t >> 6;       // wave 0..3
  const int lr   = lane & 15;
  const int lg   = lane >> 4;    // 0..3
  const int bs   = blockIdx.x;
  const float ab2 = abp[0] * kLog2e;

  // stage packed adjacency (2 words / thread)
  *(uint2*)(sm.adjs + t * 2) = *(const uint2*)(adjp + t * 2);

  // ---------------- matmul1: [Wh | f1 f2] = bf16(h) @ bf16([W | wa1 wa2]) ----------------
  const float* hblk = h + (size_t)bs * 16384;
  const int R0 = w * 32;

  bf16x8 ha[2][4];
#pragma unroll
  for (int rt = 0; rt < 2; ++rt)
#pragma unroll
    for (int kc = 0; kc < 4; ++kc) {
      const float* p = hblk + (R0 + rt * 16 + lr) * 128 + kc * 32 + lg * 8;
      f32x4 v0 = *(const f32x4*)p;
      f32x4 v1 = *(const f32x4*)(p + 4);
      union { bf16x8 v; unsigned int u[4]; } pk;
      pk.u[0] = f2bf2(v0[0], v0[1]);
      pk.u[1] = f2bf2(v0[2], v0[3]);
      pk.u[2] = f2bf2(v1[0], v1[1]);
      pk.u[3] = f2bf2(v1[2], v1[3]);
      ha[rt][kc] = pk.v;
    }

  f32x4 acc[2][9];
#pragma unroll
  for (int rt = 0; rt < 2; ++rt)
#pragma unroll
    for (int g = 0; g < 9; ++g) acc[rt][g] = (f32x4){0.f, 0.f, 0.f, 0.f};

#pragma unroll
  for (int g = 0; g < 9; ++g)
#pragma unroll
    for (int kc = 0; kc < 4; ++kc) {
      const bf16x8 bh = *(const bf16x8*)(wf + ((g * 4 + kc) * 64 + lane) * 8);
      acc[0][g] = __builtin_amdgcn_mfma_f32_16x16x32_bf16(ha[0][kc], bh, acc[0][g], 0, 0, 0);
      acc[1][g] = __builtin_amdgcn_mfma_f32_16x16x32_bf16(ha[1][kc], bh, acc[1][g], 0, 0, 0);
    }

  // ---- bias + f1/f2 scatter + Wh -> LDS (B-frag order, bf16) ----
  float wbc[8];
#pragma unroll
  for (int g = 0; g < 8; ++g) wbc[g] = Wb[g * 16 + lr];
  const float ba1 = ba[0], ba2 = ba[1];

#pragma unroll
  for (int rt = 0; rt < 2; ++rt) {
#pragma unroll
    for (int r = 0; r < 4; ++r) {
      // C/D layout: row = R0 + rt*16 + lg*4 + r, col = g*16 + lr
#pragma unroll
      for (int g = 0; g < 8; ++g) acc[rt][g][r] += wbc[g];
      const int row = R0 + rt * 16 + lg * 4 + r;
      if (lr == 0)      sm.f1s[row] = acc[rt][8][r] + ba1;
      else if (lr == 1) sm.f2s[row] = acc[rt][8][r] + ba2;
    }
#pragma unroll
    for (int g = 0; g < 8; ++g) {
      const unsigned int plo = f2bf2(acc[rt][g][0], acc[rt][g][1]);
      const unsigned int phi = f2bf2(acc[rt][g][2], acc[rt][g][3]);
      const int lp = (2 * rt + (lg >> 1)) * 16 + lr;
      const int jb = (lg & 1) * 4;
      *(uint2*)(&sm.Whs[g][w][lp][jb]) = make_uint2(plo, phi);
    }
  }
  __syncthreads();

  // ---------------- P-build: single pass, no max-sub (log2 domain, exp2) ----------------
  bf16x8 af[2][4];
  float s0 = 0.f, s1 = 0.f;
  const float f1i0 = sm.f1s[R0 + lr] + ab2;
  const float f1i1 = sm.f1s[R0 + 16 + lr] + ab2;
  const int rq0 = (R0 + lr) * 4, rq1 = (R0 + 16 + lr) * 4;
#pragma unroll
  for (int kc = 0; kc < 4; ++kc) {
    const f32x4 fv0 = *(const f32x4*)(&sm.f2s[kc * 32 + lg * 8]);
    const f32x4 fv1 = *(const f32x4*)(&sm.f2s[kc * 32 + lg * 8 + 4]);
    const unsigned int aw0 = sm.adjs[rq0 + kc];
    const unsigned int aw1 = sm.adjs[rq1 + kc];
    union { bf16x8 v; unsigned int u[4]; } pk0, pk1;
#pragma unroll
    for (int qq = 0; qq < 4; ++qq) {
      float e0[2], e1[2];
#pragma unroll
      for (int hh = 0; hh < 2; ++hh) {
        const int q = qq * 2 + hh;
        const float fj = (q < 4) ? fv0[q] : fv1[q - 4];
        const unsigned int bit = 1u << (lg * 8 + q);
        float x0 = f1i0 + fj;
        x0 = x0 >= 0.f ? x0 : kSlope * x0;
        x0 = (aw0 & bit) ? x0 : kNegInf;
        e0[hh] = exp2_hw(x0);
        float x1 = f1i1 + fj;
        x1 = x1 >= 0.f ? x1 : kSlope * x1;
        x1 = (aw1 & bit) ? x1 : kNegInf;
        e1[hh] = exp2_hw(x1);
      }
      const unsigned int u0 = f2bf2(e0[0], e0[1]);
      const unsigned int u1 = f2bf2(e1[0], e1[1]);
      pk0.u[qq] = u0;
      pk1.u[qq] = u1;
      s0 += __uint_as_float(u0 << 16) + __uint_as_float(u0 & 0xffff0000u);
      s1 += __uint_as_float(u1 << 16) + __uint_as_float(u1 & 0xffff0000u);
    }
    af[0][kc] = pk0.v;
    af[1][kc] = pk1.v;
  }
  s0 += __shfl_xor(s0, 16);
  s0 += __shfl_xor(s0, 32);
  s1 += __shfl_xor(s1, 16);
  s1 += __shfl_xor(s1, 32);
  float rs[2] = {s0, s1};

  // ---------------- matmul2: h'·l = P @ Wh ----------------
  f32x4 acc2[2][8];
#pragma unroll
  for (int rt = 0; rt < 2; ++rt)
#pragma unroll
    for (int g = 0; g < 8; ++g) acc2[rt][g] = (f32x4){0.f, 0.f, 0.f, 0.f};

#pragma unroll
  for (int g = 0; g < 8; ++g)
#pragma unroll
    for (int kc = 0; kc < 4; ++kc) {
      const bf16x8 bw = *(const bf16x8*)(&sm.Whs[g][kc][lane][0]);
      acc2[0][g] = __builtin_amdgcn_mfma_f32_16x16x32_bf16(af[0][kc], bw, acc2[0][g], 0, 0, 0);
      acc2[1][g] = __builtin_amdgcn_mfma_f32_16x16x32_bf16(af[1][kc], bw, acc2[1][g], 0, 0, 0);
    }
  __syncthreads();  // all Whs reads done before stage overwrites it

  // ---------------- normalize + elu + LDS-staged coalesced store ----------------
  float* oblk = out + (size_t)bs * 16384;
#pragma unroll
  for (int rt = 0; rt < 2; ++rt) {
    float inv[4];
#pragma unroll
    for (int r = 0; r < 4; ++r) {
      const float lsum = __shfl(rs[rt], (lane & 48) | (lg * 4 + r));
      inv[r] = __builtin_amdgcn_rcpf(lsum);
    }
#pragma unroll
    for (int r = 0; r < 4; ++r)
#pragma unroll
      for (int g = 0; g < 8; ++g) {
        float v = acc2[rt][g][r] * inv[r];
        v = v > 0.f ? v : __expf(v) - 1.0f;
        smu.stage[w][lg * 4 + r][g * 16 + lr] = v;  // 2-way bank aliasing = free
      }
    // wave-local RAW on stage: compiler inserts lgkmcnt
#pragma unroll
    for (int sstep = 0; sstep < 8; ++sstep) {
      const int row16 = ((sstep & 1) << 3) + (lane >> 3);
      const int cd    = ((sstep >> 1) << 5) + ((lane & 7) << 2);
      f32x4 vv = *(const f32x4*)(&smu.stage[w][row16][cd]);
      *(f32x4*)(oblk + (size_t)(R0 + rt * 16 + row16) * 128 + cd) = vv;
    }
  }
}

}  // namespace

extern "C" void kernel_launch(void* const* d_in, const int* in_sizes, int n_in,
                              void* d_out, int out_size, void* d_ws, size_t ws_size,
                              hipStream_t stream) {
  const float* h   = (const float*)d_in[0];
  const float* Ww  = (const float*)d_in[1];
  const float* Wb  = (const float*)d_in[2];
  const float* a1v = (const float*)d_in[3];
  const float* a2v = (const float*)d_in[4];
  const float* ab  = (const float*)d_in[5];
  const int*   adj = (const int*)d_in[6];
  float* out = (float*)d_out;

  unsigned short* wf   = (unsigned short*)d_ws;
  unsigned int*   adjp = (unsigned int*)((char*)d_ws + 36864);
  float*          wa1  = (float*)((char*)d_ws + 38912);
  float*          wa2  = (float*)((char*)d_ws + 39424);
  float*          ba   = (float*)((char*)d_ws + 39936);

  hipLaunchKernelGGL(prep1, dim3(1), dim3(256), 0, stream, Ww, Wb, a1v, a2v, wa1, wa2, ba);
  hipLaunchKernelGGL(prep2, dim3(72), dim3(256), 0, stream, Ww, adj, wa1, wa2, wf, adjp);

  const int BS = in_sizes[0] / 16384;  // 1024
  hipLaunchKernelGGL(gat_mfma, dim3(BS), dim3(256), 0, stream,
                     h, Wb, ab, wf, adjp, ba, out);
}